// Round 4
// baseline (173.467 us; speedup 1.0000x reference)
//
#include <hip/hip_runtime.h>
#include <hip/hip_bf16.h>
#include <stdint.h>

#define SEQ 4096
#define DIN 1024
#define DOUT 1024

typedef __bf16 bf16;
typedef __bf16 bf16x4v __attribute__((ext_vector_type(4)));
typedef __bf16 bf16x8v __attribute__((ext_vector_type(8)));
typedef float f32x4 __attribute__((ext_vector_type(4)));

#define AS1 __attribute__((address_space(1)))
#define AS3 __attribute__((address_space(3)))

__device__ __forceinline__ void load_lds16(const void* g, void* l) {
  __builtin_amdgcn_global_load_lds((const AS1 uint32_t*)g, (AS3 uint32_t*)l, 16, 0, 0);
}

__device__ __forceinline__ int imin(int a, int b) { return a < b ? a : b; }

// ---------------- fused cast fp32 -> bf16 for x, Wq, Wk, Wv -------------------
__global__ __launch_bounds__(256) void cast_all_kernel(
    const float* __restrict__ x, const float* __restrict__ wq,
    const float* __restrict__ wk, const float* __restrict__ wv,
    bf16* __restrict__ xb, bf16* __restrict__ wqb,
    bf16* __restrict__ wkb, bf16* __restrict__ wvb) {
  const int y = blockIdx.y;
  const float* in = (y == 0) ? x : (y == 1) ? wq : (y == 2) ? wk : wv;
  bf16* out = (y == 0) ? xb : (y == 1) ? wqb : (y == 2) ? wkb : wvb;
  const int n = (y == 0) ? SEQ * DIN : DOUT * DIN;
  int i = (blockIdx.x * 256 + threadIdx.x) * 4;
  if (i >= n) return;
  float4 v = *reinterpret_cast<const float4*>(in + i);
  bf16x4v o;
  o[0] = (bf16)v.x; o[1] = (bf16)v.y; o[2] = (bf16)v.z; o[3] = (bf16)v.w;
  *reinterpret_cast<bf16x4v*>(out + i) = o;
}

// ---------------- BT GEMM core: depth-2 counted-vmcnt pipeline ----------------
// C[128x128] += A[brow..][k] * B[bcol..][k]^T over k in [kbeg,kend).
// A: [M x lda] bf16 row-major, B: [N x ldb] bf16 row-major (K contiguous both).
// 256 threads = 4 waves (2x2), each wave 64x64 out = 4x4 frags of 16x16x32 MFMA.
// At/Bt: 3 buffers of 128x32 bf16 each (8 KB/buffer) -> 48 KB total LDS.
// LDS layout is column-XOR-swizzled: linear slot (r,c) holds global (r, c^s(r)),
// s(r) = (r&3)<<4, achieved by pre-swizzling the global SOURCE column
// (global_load_lds dest must stay linear). Reads apply the same XOR.
__device__ __forceinline__ void gemm_bt_core(const bf16* __restrict__ A,
                                             const bf16* __restrict__ B,
                                             int lda, int ldb, int brow, int bcol,
                                             int kbeg, int kend, f32x4 acc[4][4],
                                             bf16* At, bf16* Bt) {
  const int tid = threadIdx.x;
  const int lane = tid & 63;

  // staging: 2 issues per operand per tile (256 thr * 16B = 4KB each)
  const int off0 = tid * 16;        // [0, 4096)
  const int off1 = off0 + 4096;     // [4096, 8192)
  const int r0 = off0 >> 6, c0 = (off0 & 63) ^ ((r0 & 3) << 4);
  const int r1 = off1 >> 6, c1 = (off1 & 63) ^ ((r1 & 3) << 4);
  const char* A0 = (const char*)A + (size_t)(brow + r0) * (size_t)(lda * 2) + c0;
  const char* A1 = (const char*)A + (size_t)(brow + r1) * (size_t)(lda * 2) + c1;
  const char* B0 = (const char*)B + (size_t)(bcol + r0) * (size_t)(ldb * 2) + c0;
  const char* B1 = (const char*)B + (size_t)(bcol + r1) * (size_t)(ldb * 2) + c1;

  const int wr = (tid >> 7) & 1;
  const int wc = (tid >> 6) & 1;
  const int lrow = lane & 15;
  // swizzled k-group byte offset (row&3 == lrow&3 for all mt/nt/wr/wc)
  const int lks = ((lane >> 4) * 16) ^ ((lrow & 3) << 4);

  char* AtB = (char*)At;
  char* BtB = (char*)Bt;

#define STAGE(buf, kk) do {                                   \
    const size_t kb_ = (size_t)(kk) * 2;                      \
    load_lds16(A0 + kb_, AtB + (buf) * 8192 + off0);          \
    load_lds16(A1 + kb_, AtB + (buf) * 8192 + off1);          \
    load_lds16(B0 + kb_, BtB + (buf) * 8192 + off0);          \
    load_lds16(B1 + kb_, BtB + (buf) * 8192 + off1);          \
  } while (0)

  const int total = (kend - kbeg) >> 5;   // number of 32-wide K tiles (>=1)
  const int kmax = kend - 32;             // clamp target for dup tail stages

  // prologue: stage tiles 0 and 1 (1 = clamped dup if total==1)
  STAGE(0, kbeg);
  STAGE(1, imin(kbeg + 32, kmax));
  asm volatile("s_waitcnt vmcnt(4)" ::: "memory");  // tile 0 landed
  __builtin_amdgcn_s_barrier();
  __builtin_amdgcn_sched_barrier(0);

  int cur = 0;
  for (int t = 0; t < total; ++t) {
    // stage tile t+2 (clamped dup near the tail; L2-hit, never consumed)
    int nxt = cur + 2; if (nxt >= 3) nxt -= 3;
    STAGE(nxt, imin(kbeg + (t + 2) * 32, kmax));

    const char* Ab = AtB + cur * 8192;
    const char* Bb = BtB + cur * 8192;
    bf16x8v a[4], b[4];
#pragma unroll
    for (int mt = 0; mt < 4; ++mt)
      a[mt] = *(const bf16x8v*)(Ab + ((wr * 64 + mt * 16 + lrow) * 64 + lks));
#pragma unroll
    for (int nt = 0; nt < 4; ++nt)
      b[nt] = *(const bf16x8v*)(Bb + ((wc * 64 + nt * 16 + lrow) * 64 + lks));
#pragma unroll
    for (int mt = 0; mt < 4; ++mt)
#pragma unroll
      for (int nt = 0; nt < 4; ++nt)
        acc[mt][nt] = __builtin_amdgcn_mfma_f32_16x16x32_bf16(a[mt], b[nt], acc[mt][nt], 0, 0, 0);

    // counted wait: all but the newest stage (4 loads) landed -> tile t+1 ready
    asm volatile("s_waitcnt vmcnt(4)" ::: "memory");
    __builtin_amdgcn_s_barrier();
    __builtin_amdgcn_sched_barrier(0);
    if (++cur == 3) cur = 0;
  }
#undef STAGE
}

#define ACC_INIT()                    \
  f32x4 acc[4][4];                    \
  {                                   \
    f32x4 z = {0.f, 0.f, 0.f, 0.f};  \
    for (int m = 0; m < 4; ++m)       \
      for (int n = 0; n < 4; ++n) acc[m][n] = z; \
  }

#define GEMM_LDS()                    \
  __shared__ bf16 At[3 * 128 * 32];   \
  __shared__ bf16 Bt[3 * 128 * 32];

// ---------------- QKV projection: Q,K row-major bf16; V written transposed ----
__global__ __launch_bounds__(256) void qkv_kernel(const bf16* __restrict__ xb,
                                                  const bf16* __restrict__ Wq,
                                                  const bf16* __restrict__ Wk,
                                                  const bf16* __restrict__ Wv,
                                                  bf16* __restrict__ Q,
                                                  bf16* __restrict__ K,
                                                  bf16* __restrict__ Vt) {
  GEMM_LDS();
  const int bj = blockIdx.x, bi = blockIdx.y, z = blockIdx.z;
  const bf16* W = (z == 0) ? Wq : (z == 1) ? Wk : Wv;
  ACC_INIT();
  gemm_bt_core(xb, W, DIN, DIN, bi * 128, bj * 128, 0, DIN, acc, At, Bt);
  const int lane = threadIdx.x & 63;
  const int wr = (threadIdx.x >> 7) & 1, wc = (threadIdx.x >> 6) & 1;
  const int rbase = bi * 128 + wr * 64 + ((lane >> 4) << 2);
  const int cbase = bj * 128 + wc * 64 + (lane & 15);
  if (z < 2) {
    bf16* O = (z == 0) ? Q : K;
#pragma unroll
    for (int mt = 0; mt < 4; ++mt)
#pragma unroll
      for (int nt = 0; nt < 4; ++nt)
#pragma unroll
        for (int j = 0; j < 4; ++j)
          O[(size_t)(rbase + mt * 16 + j) * DOUT + (cbase + nt * 16)] = (bf16)acc[mt][nt][j];
  } else {
#pragma unroll
    for (int mt = 0; mt < 4; ++mt)
#pragma unroll
      for (int nt = 0; nt < 4; ++nt)
#pragma unroll
        for (int j = 0; j < 4; ++j)
          Vt[(size_t)(cbase + nt * 16) * SEQ + (rbase + mt * 16 + j)] = (bf16)acc[mt][nt][j];
  }
}

// ---------------- scores = Q @ K^T * scale, exact lower-triangle grid ---------
__global__ __launch_bounds__(256) void scores_kernel(const bf16* __restrict__ Q,
                                                     const bf16* __restrict__ Km,
                                                     float* __restrict__ Sc) {
  const int t = blockIdx.x;  // 0..527 triangular index
  int bi = (int)((sqrtf(8.0f * (float)t + 1.0f) - 1.0f) * 0.5f);
  while ((bi + 1) * (bi + 2) / 2 <= t) ++bi;
  while (bi * (bi + 1) / 2 > t) --bi;
  const int bj = t - bi * (bi + 1) / 2;
  GEMM_LDS();
  ACC_INIT();
  gemm_bt_core(Q, Km, DOUT, DOUT, bi * 128, bj * 128, 0, DOUT, acc, At, Bt);
  const int lane = threadIdx.x & 63;
  const int wr = (threadIdx.x >> 7) & 1, wc = (threadIdx.x >> 6) & 1;
  const int rbase = bi * 128 + wr * 64 + ((lane >> 4) << 2);
  const int cbase = bj * 128 + wc * 64 + (lane & 15);
  const float scale = 0.03125f;  // 1/sqrt(1024)
#pragma unroll
  for (int mt = 0; mt < 4; ++mt)
#pragma unroll
    for (int nt = 0; nt < 4; ++nt)
#pragma unroll
      for (int j = 0; j < 4; ++j)
        Sc[(size_t)(rbase + mt * 16 + j) * SEQ + (cbase + nt * 16)] = acc[mt][nt][j] * scale;
}

// ---------------- row softmax (vectorized): P[r][0..r]=softmax, zero-pad ------
__global__ __launch_bounds__(256) void softmax_kernel(const float* __restrict__ Sc,
                                                      bf16* __restrict__ P) {
  __shared__ float rowbuf[SEQ];
  __shared__ float red[8];
  const int r = blockIdx.x;
  const int n = r + 1;
  const int nw4 = ((r >> 7) + 1) << 5;  // padded row length / 4
  const int tid = threadIdx.x;
  const float* src = Sc + (size_t)r * SEQ;
  const float NEG = -__builtin_inff();

  float lmax = NEG;
  for (int g = tid; g < nw4; g += 256) {
    float4 v = reinterpret_cast<const float4*>(src)[g];
    const int b = g * 4;
    v.x = (b + 0 < n) ? v.x : NEG;
    v.y = (b + 1 < n) ? v.y : NEG;
    v.z = (b + 2 < n) ? v.z : NEG;
    v.w = (b + 3 < n) ? v.w : NEG;
    reinterpret_cast<float4*>(rowbuf)[g] = v;
    lmax = fmaxf(fmaxf(lmax, fmaxf(v.x, v.y)), fmaxf(v.z, v.w));
  }
#pragma unroll
  for (int m = 32; m >= 1; m >>= 1) lmax = fmaxf(lmax, __shfl_xor(lmax, m, 64));
  if ((tid & 63) == 0) red[tid >> 6] = lmax;
  __syncthreads();
  const float rmax = fmaxf(fmaxf(red[0], red[1]), fmaxf(red[2], red[3]));

  float lsum = 0.f;
  for (int g = tid; g < nw4; g += 256) {
    float4 v = reinterpret_cast<const float4*>(rowbuf)[g];
    v.x = __expf(v.x - rmax);
    v.y = __expf(v.y - rmax);
    v.z = __expf(v.z - rmax);
    v.w = __expf(v.w - rmax);
    reinterpret_cast<float4*>(rowbuf)[g] = v;
    lsum += v.x + v.y + v.z + v.w;
  }
#pragma unroll
  for (int m = 32; m >= 1; m >>= 1) lsum += __shfl_xor(lsum, m, 64);
  if ((tid & 63) == 0) red[4 + (tid >> 6)] = lsum;
  __syncthreads();
  const float inv = 1.0f / (red[4] + red[5] + red[6] + red[7]);

  bf16* dst = P + (size_t)r * SEQ;
  for (int g = tid; g < nw4; g += 256) {
    float4 v = reinterpret_cast<const float4*>(rowbuf)[g];
    bf16x4v o;
    o[0] = (bf16)(v.x * inv);
    o[1] = (bf16)(v.y * inv);
    o[2] = (bf16)(v.z * inv);
    o[3] = (bf16)(v.w * inv);
    *reinterpret_cast<bf16x4v*>(dst + g * 4) = o;
  }
}

// ---------------- out += P @ V (balanced split-K, atomic accumulate) ----------
// blockIdx.x = bj (d-out col block), blockIdx.y = linear chunk over all bi.
// Per block-row bi: Ti=(bi+1)*4 BK-iters split into nch=ceil((bi+1)/8) chunks
// of <=32 iters, balanced. bi<8 has a single writer -> plain store.
__global__ __launch_bounds__(256) void pv_kernel(const bf16* __restrict__ P,
                                                 const bf16* __restrict__ Vt,
                                                 float* __restrict__ Out) {
  GEMM_LDS();
  const int bj = blockIdx.x;
  int c = blockIdx.y, bi = 0;
  for (;;) {
    const int nch = (bi + 8) >> 3;  // ceil((bi+1)/8)
    if (c < nch) break;
    c -= nch; ++bi;
  }
  const int nch = (bi + 8) >> 3;
  const int Ti = (bi + 1) * 4;
  const int base = Ti / nch, rem = Ti % nch;
  const int it0 = c * base + imin(c, rem);
  const int itn = base + (c < rem ? 1 : 0);
  const int k0 = it0 * 32;
  const int kend = k0 + itn * 32;
  ACC_INIT();
  gemm_bt_core(P, Vt, SEQ, SEQ, bi * 128, bj * 128, k0, kend, acc, At, Bt);
  const int lane = threadIdx.x & 63;
  const int wr = (threadIdx.x >> 7) & 1, wc = (threadIdx.x >> 6) & 1;
  const int rbase = bi * 128 + wr * 64 + ((lane >> 4) << 2);
  const int cbase = bj * 128 + wc * 64 + (lane & 15);
  if (nch == 1) {
#pragma unroll
    for (int mt = 0; mt < 4; ++mt)
#pragma unroll
      for (int nt = 0; nt < 4; ++nt)
#pragma unroll
        for (int j = 0; j < 4; ++j)
          Out[(size_t)(rbase + mt * 16 + j) * DOUT + (cbase + nt * 16)] = acc[mt][nt][j];
  } else {
#pragma unroll
    for (int mt = 0; mt < 4; ++mt)
#pragma unroll
      for (int nt = 0; nt < 4; ++nt)
#pragma unroll
        for (int j = 0; j < 4; ++j)
          atomicAdd(&Out[(size_t)(rbase + mt * 16 + j) * DOUT + (cbase + nt * 16)],
                    acc[mt][nt][j]);
  }
}

extern "C" void kernel_launch(void* const* d_in, const int* in_sizes, int n_in,
                              void* d_out, int out_size, void* d_ws, size_t ws_size,
                              hipStream_t stream) {
  const float* x  = (const float*)d_in[0];
  const float* Wq = (const float*)d_in[1];
  const float* Wk = (const float*)d_in[2];
  const float* Wv = (const float*)d_in[3];
  float* Out = (float*)d_out;

  char* base = (char*)d_ws;
  bf16* xb  = (bf16*)(base + 0);          //  8 MB  [4096x1024]
  bf16* wqb = (bf16*)(base + 8388608);    //  2 MB
  bf16* wkb = (bf16*)(base + 10485760);   //  2 MB
  bf16* wvb = (bf16*)(base + 12582912);   //  2 MB
  bf16* Qb  = (bf16*)(base + 14680064);   //  8 MB
  bf16* Kb  = (bf16*)(base + 23068672);   //  8 MB
  bf16* Vtb = (bf16*)(base + 31457280);   //  8 MB  [1024x4096] transposed
  float* Sc = (float*)(base + 39845888);  // 64 MB  [4096x4096] fp32
  bf16* P   = (bf16*)(base + 106954752);  // 32 MB  [4096x4096] bf16
  // total ws use: 140,509,184 bytes

  hipMemsetAsync(d_out, 0, (size_t)out_size * sizeof(float), stream);

  cast_all_kernel<<<dim3(4096, 4), 256, 0, stream>>>(x, Wq, Wk, Wv, xb, wqb, wkb, wvb);

  qkv_kernel<<<dim3(DOUT / 128, SEQ / 128, 3), 256, 0, stream>>>(xb, wqb, wkb, wvb, Qb, Kb, Vtb);
  scores_kernel<<<528, 256, 0, stream>>>(Qb, Kb, Sc);
  softmax_kernel<<<SEQ, 256, 0, stream>>>(Sc, P);
  pv_kernel<<<dim3(DOUT / 128, 80), 256, 0, stream>>>(P, Vtb, Out);
}

// Round 5
// 153.331 us; speedup vs baseline: 1.1313x; 1.1313x over previous
//
#include <hip/hip_runtime.h>
#include <hip/hip_bf16.h>
#include <stdint.h>

#define SEQ 4096
#define DIN 1024
#define DOUT 1024

typedef __bf16 bf16;
typedef __bf16 bf16x4v __attribute__((ext_vector_type(4)));
typedef __bf16 bf16x8v __attribute__((ext_vector_type(8)));
typedef float f32x4 __attribute__((ext_vector_type(4)));

#define AS1 __attribute__((address_space(1)))
#define AS3 __attribute__((address_space(3)))

__device__ __forceinline__ void load_lds16(const void* g, void* l) {
  __builtin_amdgcn_global_load_lds((const AS1 uint32_t*)g, (AS3 uint32_t*)l, 16, 0, 0);
}

__device__ __forceinline__ int imin(int a, int b) { return a < b ? a : b; }

// XCD-chunked bijective swizzle (T1). Valid because nwg % 8 == 0 for all grids.
// Consecutive LOGICAL ids land on the same XCD -> order logicals so that
// neighbors share the A-operand panel (bj innermost).
__device__ __forceinline__ int xcd_chunk(int orig, int nwg) {
  return (orig & 7) * (nwg >> 3) + (orig >> 3);
}

// ---------------- fused cast fp32 -> bf16 for x, Wq, Wk, Wv (exact 1D grid) ---
__global__ __launch_bounds__(256) void cast_all_kernel(
    const float* __restrict__ x, const float* __restrict__ wq,
    const float* __restrict__ wk, const float* __restrict__ wv,
    bf16* __restrict__ xb, bf16* __restrict__ wqb,
    bf16* __restrict__ wkb, bf16* __restrict__ wvb) {
  const int id = blockIdx.x;
  const float* in; bf16* out; int blk;
  if (id < 4096) {
    in = x; out = xb; blk = id;
  } else {
    const int w = (id - 4096) >> 10;
    blk = (id - 4096) & 1023;
    in = (w == 0) ? wq : (w == 1) ? wk : wv;
    out = (w == 0) ? wqb : (w == 1) ? wkb : wvb;
  }
  const int i = (blk * 256 + threadIdx.x) * 4;
  float4 v = *reinterpret_cast<const float4*>(in + i);
  bf16x4v o;
  o[0] = (bf16)v.x; o[1] = (bf16)v.y; o[2] = (bf16)v.z; o[3] = (bf16)v.w;
  *reinterpret_cast<bf16x4v*>(out + i) = o;
}

// ---------------- BT GEMM core: depth-2 counted-vmcnt pipeline ----------------
// C[128x128] += A[brow..][k] * B[bcol..][k]^T over k in [kbeg,kend).
// A: [M x lda] bf16 row-major, B: [N x ldb] bf16 row-major (K contiguous both).
// 256 threads = 4 waves (2x2), each wave 64x64 out = 4x4 frags of 16x16x32 MFMA.
// At/Bt: 3 buffers of 128x32 bf16 each (8 KB/buffer) -> 48 KB total LDS.
__device__ __forceinline__ void gemm_bt_core(const bf16* __restrict__ A,
                                             const bf16* __restrict__ B,
                                             int lda, int ldb, int brow, int bcol,
                                             int kbeg, int kend, f32x4 acc[4][4],
                                             bf16* At, bf16* Bt) {
  const int tid = threadIdx.x;
  const int lane = tid & 63;

  // staging: 2 issues per operand per tile (256 thr * 16B = 4KB each)
  const int off0 = tid * 16;        // [0, 4096)
  const int off1 = off0 + 4096;     // [4096, 8192)
  const int r0 = off0 >> 6, c0 = off0 & 63;   // tile row / byte-in-row (64B rows)
  const int r1 = off1 >> 6, c1 = off1 & 63;
  const char* A0 = (const char*)A + (size_t)(brow + r0) * (size_t)(lda * 2) + c0;
  const char* A1 = (const char*)A + (size_t)(brow + r1) * (size_t)(lda * 2) + c1;
  const char* B0 = (const char*)B + (size_t)(bcol + r0) * (size_t)(ldb * 2) + c0;
  const char* B1 = (const char*)B + (size_t)(bcol + r1) * (size_t)(ldb * 2) + c1;

  const int wr = (tid >> 7) & 1;
  const int wc = (tid >> 6) & 1;
  const int lrow = lane & 15;
  const int lk = (lane >> 4) * 16;  // byte offset of this lane's k-group

  char* AtB = (char*)At;
  char* BtB = (char*)Bt;

#define STAGE(buf, kk) do {                                   \
    const size_t kb_ = (size_t)(kk) * 2;                      \
    load_lds16(A0 + kb_, AtB + (buf) * 8192 + off0);          \
    load_lds16(A1 + kb_, AtB + (buf) * 8192 + off1);          \
    load_lds16(B0 + kb_, BtB + (buf) * 8192 + off0);          \
    load_lds16(B1 + kb_, BtB + (buf) * 8192 + off1);          \
  } while (0)

  const int total = (kend - kbeg) >> 5;   // number of 32-wide K tiles (>=1)
  const int kmax = kend - 32;             // clamp target for dup tail stages

  // prologue: stage tiles 0 and 1 (1 = clamped dup if total==1)
  STAGE(0, kbeg);
  STAGE(1, imin(kbeg + 32, kmax));
  asm volatile("s_waitcnt vmcnt(4)" ::: "memory");  // tile 0 landed
  __builtin_amdgcn_s_barrier();
  __builtin_amdgcn_sched_barrier(0);

  int cur = 0;
  for (int t = 0; t < total; ++t) {
    // stage tile t+2 (clamped dup near the tail; L2-hit, never consumed)
    int nxt = cur + 2; if (nxt >= 3) nxt -= 3;
    STAGE(nxt, imin(kbeg + (t + 2) * 32, kmax));

    const char* Ab = AtB + cur * 8192;
    const char* Bb = BtB + cur * 8192;
    bf16x8v a[4], b[4];
#pragma unroll
    for (int mt = 0; mt < 4; ++mt)
      a[mt] = *(const bf16x8v*)(Ab + ((wr * 64 + mt * 16 + lrow) * 64 + lk));
#pragma unroll
    for (int nt = 0; nt < 4; ++nt)
      b[nt] = *(const bf16x8v*)(Bb + ((wc * 64 + nt * 16 + lrow) * 64 + lk));
#pragma unroll
    for (int mt = 0; mt < 4; ++mt)
#pragma unroll
      for (int nt = 0; nt < 4; ++nt)
        acc[mt][nt] = __builtin_amdgcn_mfma_f32_16x16x32_bf16(a[mt], b[nt], acc[mt][nt], 0, 0, 0);

    // counted wait: all but the newest stage (4 loads) landed -> tile t+1 ready
    asm volatile("s_waitcnt vmcnt(4)" ::: "memory");
    __builtin_amdgcn_s_barrier();
    __builtin_amdgcn_sched_barrier(0);
    if (++cur == 3) cur = 0;
  }
#undef STAGE
}

#define ACC_INIT()                    \
  f32x4 acc[4][4];                    \
  {                                   \
    f32x4 z = {0.f, 0.f, 0.f, 0.f};  \
    for (int m = 0; m < 4; ++m)       \
      for (int n = 0; n < 4; ++n) acc[m][n] = z; \
  }

#define GEMM_LDS()                    \
  __shared__ bf16 At[3 * 128 * 32];   \
  __shared__ bf16 Bt[3 * 128 * 32];

// ---------------- QKV projection: Q,K row-major bf16; V written transposed ----
// 1D grid of 768, XCD-chunked; logical order: z outer, bi, bj inner (8).
__global__ __launch_bounds__(256) void qkv_kernel(const bf16* __restrict__ xb,
                                                  const bf16* __restrict__ Wq,
                                                  const bf16* __restrict__ Wk,
                                                  const bf16* __restrict__ Wv,
                                                  bf16* __restrict__ Q,
                                                  bf16* __restrict__ K,
                                                  bf16* __restrict__ Vt) {
  GEMM_LDS();
  const int l = xcd_chunk(blockIdx.x, 768);
  const int z = l >> 8;
  const int bi = (l & 255) >> 3;
  const int bj = l & 7;
  const bf16* W = (z == 0) ? Wq : (z == 1) ? Wk : Wv;
  ACC_INIT();
  gemm_bt_core(xb, W, DIN, DIN, bi * 128, bj * 128, 0, DIN, acc, At, Bt);
  const int lane = threadIdx.x & 63;
  const int wr = (threadIdx.x >> 7) & 1, wc = (threadIdx.x >> 6) & 1;
  const int rbase = bi * 128 + wr * 64 + ((lane >> 4) << 2);
  const int cbase = bj * 128 + wc * 64 + (lane & 15);
  if (z < 2) {
    bf16* O = (z == 0) ? Q : K;
#pragma unroll
    for (int mt = 0; mt < 4; ++mt)
#pragma unroll
      for (int nt = 0; nt < 4; ++nt)
#pragma unroll
        for (int j = 0; j < 4; ++j)
          O[(size_t)(rbase + mt * 16 + j) * DOUT + (cbase + nt * 16)] = (bf16)acc[mt][nt][j];
  } else {
#pragma unroll
    for (int mt = 0; mt < 4; ++mt)
#pragma unroll
      for (int nt = 0; nt < 4; ++nt)
#pragma unroll
        for (int j = 0; j < 4; ++j)
          Vt[(size_t)(cbase + nt * 16) * SEQ + (rbase + mt * 16 + j)] = (bf16)acc[mt][nt][j];
  }
}

// ---------------- scores = Q @ K^T * scale, exact lower-triangle grid ---------
// 1D grid of 528 triangular (bi-major, bj inner), XCD-chunked.
__global__ __launch_bounds__(256) void scores_kernel(const bf16* __restrict__ Q,
                                                     const bf16* __restrict__ Km,
                                                     float* __restrict__ Sc) {
  const int t = xcd_chunk(blockIdx.x, 528);
  int bi = (int)((sqrtf(8.0f * (float)t + 1.0f) - 1.0f) * 0.5f);
  while ((bi + 1) * (bi + 2) / 2 <= t) ++bi;
  while (bi * (bi + 1) / 2 > t) --bi;
  const int bj = t - bi * (bi + 1) / 2;
  GEMM_LDS();
  ACC_INIT();
  gemm_bt_core(Q, Km, DOUT, DOUT, bi * 128, bj * 128, 0, DOUT, acc, At, Bt);
  const int lane = threadIdx.x & 63;
  const int wr = (threadIdx.x >> 7) & 1, wc = (threadIdx.x >> 6) & 1;
  const int rbase = bi * 128 + wr * 64 + ((lane >> 4) << 2);
  const int cbase = bj * 128 + wc * 64 + (lane & 15);
  const float scale = 0.03125f;  // 1/sqrt(1024)
#pragma unroll
  for (int mt = 0; mt < 4; ++mt)
#pragma unroll
    for (int nt = 0; nt < 4; ++nt)
#pragma unroll
      for (int j = 0; j < 4; ++j)
        Sc[(size_t)(rbase + mt * 16 + j) * SEQ + (cbase + nt * 16)] = acc[mt][nt][j] * scale;
}

// ---------------- row softmax (vectorized): P[r][0..r]=softmax, zero-pad ------
__global__ __launch_bounds__(256) void softmax_kernel(const float* __restrict__ Sc,
                                                      bf16* __restrict__ P) {
  __shared__ float rowbuf[SEQ];
  __shared__ float red[8];
  const int r = blockIdx.x;
  const int n = r + 1;
  const int nw4 = ((r >> 7) + 1) << 5;  // padded row length / 4
  const int tid = threadIdx.x;
  const float* src = Sc + (size_t)r * SEQ;
  const float NEG = -__builtin_inff();

  float lmax = NEG;
  for (int g = tid; g < nw4; g += 256) {
    float4 v = reinterpret_cast<const float4*>(src)[g];
    const int b = g * 4;
    v.x = (b + 0 < n) ? v.x : NEG;
    v.y = (b + 1 < n) ? v.y : NEG;
    v.z = (b + 2 < n) ? v.z : NEG;
    v.w = (b + 3 < n) ? v.w : NEG;
    reinterpret_cast<float4*>(rowbuf)[g] = v;
    lmax = fmaxf(fmaxf(lmax, fmaxf(v.x, v.y)), fmaxf(v.z, v.w));
  }
#pragma unroll
  for (int m = 32; m >= 1; m >>= 1) lmax = fmaxf(lmax, __shfl_xor(lmax, m, 64));
  if ((tid & 63) == 0) red[tid >> 6] = lmax;
  __syncthreads();
  const float rmax = fmaxf(fmaxf(red[0], red[1]), fmaxf(red[2], red[3]));

  float lsum = 0.f;
  for (int g = tid; g < nw4; g += 256) {
    float4 v = reinterpret_cast<const float4*>(rowbuf)[g];
    v.x = __expf(v.x - rmax);
    v.y = __expf(v.y - rmax);
    v.z = __expf(v.z - rmax);
    v.w = __expf(v.w - rmax);
    reinterpret_cast<float4*>(rowbuf)[g] = v;
    lsum += v.x + v.y + v.z + v.w;
  }
#pragma unroll
  for (int m = 32; m >= 1; m >>= 1) lsum += __shfl_xor(lsum, m, 64);
  if ((tid & 63) == 0) red[4 + (tid >> 6)] = lsum;
  __syncthreads();
  const float inv = 1.0f / (red[4] + red[5] + red[6] + red[7]);

  bf16* dst = P + (size_t)r * SEQ;
  for (int g = tid; g < nw4; g += 256) {
    float4 v = reinterpret_cast<const float4*>(rowbuf)[g];
    bf16x4v o;
    o[0] = (bf16)(v.x * inv);
    o[1] = (bf16)(v.y * inv);
    o[2] = (bf16)(v.z * inv);
    o[3] = (bf16)(v.w * inv);
    *reinterpret_cast<bf16x4v*>(dst + g * 4) = o;
  }
}

// ---------------- out += P @ V (balanced split-K, atomic accumulate) ----------
// 1D grid of 640 = 80 chunk-slots x 8 bj (bj innermost), XCD-chunked.
// Per block-row bi: Ti=(bi+1)*4 BK-iters split into nch=ceil((bi+1)/8) chunks
// of <=32 iters, balanced. bi<8 has a single writer -> plain store.
__global__ __launch_bounds__(256) void pv_kernel(const bf16* __restrict__ P,
                                                 const bf16* __restrict__ Vt,
                                                 float* __restrict__ Out) {
  GEMM_LDS();
  const int l = xcd_chunk(blockIdx.x, 640);
  const int bj = l & 7;
  int c = l >> 3, bi = 0;
  for (;;) {
    const int nch = (bi + 8) >> 3;  // ceil((bi+1)/8)
    if (c < nch) break;
    c -= nch; ++bi;
  }
  const int nch = (bi + 8) >> 3;
  const int Ti = (bi + 1) * 4;
  const int base = Ti / nch, rem = Ti % nch;
  const int it0 = c * base + imin(c, rem);
  const int itn = base + (c < rem ? 1 : 0);
  const int k0 = it0 * 32;
  const int kend = k0 + itn * 32;
  ACC_INIT();
  gemm_bt_core(P, Vt, SEQ, SEQ, bi * 128, bj * 128, k0, kend, acc, At, Bt);
  const int lane = threadIdx.x & 63;
  const int wr = (threadIdx.x >> 7) & 1, wc = (threadIdx.x >> 6) & 1;
  const int rbase = bi * 128 + wr * 64 + ((lane >> 4) << 2);
  const int cbase = bj * 128 + wc * 64 + (lane & 15);
  if (nch == 1) {
#pragma unroll
    for (int mt = 0; mt < 4; ++mt)
#pragma unroll
      for (int nt = 0; nt < 4; ++nt)
#pragma unroll
        for (int j = 0; j < 4; ++j)
          Out[(size_t)(rbase + mt * 16 + j) * DOUT + (cbase + nt * 16)] = acc[mt][nt][j];
  } else {
#pragma unroll
    for (int mt = 0; mt < 4; ++mt)
#pragma unroll
      for (int nt = 0; nt < 4; ++nt)
#pragma unroll
        for (int j = 0; j < 4; ++j)
          atomicAdd(&Out[(size_t)(rbase + mt * 16 + j) * DOUT + (cbase + nt * 16)],
                    acc[mt][nt][j]);
  }
}

extern "C" void kernel_launch(void* const* d_in, const int* in_sizes, int n_in,
                              void* d_out, int out_size, void* d_ws, size_t ws_size,
                              hipStream_t stream) {
  const float* x  = (const float*)d_in[0];
  const float* Wq = (const float*)d_in[1];
  const float* Wk = (const float*)d_in[2];
  const float* Wv = (const float*)d_in[3];
  float* Out = (float*)d_out;

  char* base = (char*)d_ws;
  bf16* xb  = (bf16*)(base + 0);          //  8 MB  [4096x1024]
  bf16* wqb = (bf16*)(base + 8388608);    //  2 MB
  bf16* wkb = (bf16*)(base + 10485760);   //  2 MB
  bf16* wvb = (bf16*)(base + 12582912);   //  2 MB
  bf16* Qb  = (bf16*)(base + 14680064);   //  8 MB
  bf16* Kb  = (bf16*)(base + 23068672);   //  8 MB
  bf16* Vtb = (bf16*)(base + 31457280);   //  8 MB  [1024x4096] transposed
  float* Sc = (float*)(base + 39845888);  // 64 MB  [4096x4096] fp32
  bf16* P   = (bf16*)(base + 106954752);  // 32 MB  [4096x4096] bf16
  // total ws use: 140,509,184 bytes

  hipMemsetAsync(d_out, 0, (size_t)out_size * sizeof(float), stream);

  cast_all_kernel<<<7168, 256, 0, stream>>>(x, Wq, Wk, Wv, xb, wqb, wkb, wvb);

  qkv_kernel<<<768, 256, 0, stream>>>(xb, wqb, wkb, wvb, Qb, Kb, Vtb);
  scores_kernel<<<528, 256, 0, stream>>>(Qb, Kb, Sc);
  softmax_kernel<<<SEQ, 256, 0, stream>>>(Sc, P);
  pv_kernel<<<640, 256, 0, stream>>>(P, Vtb, Out);
}

// Round 6
// 146.838 us; speedup vs baseline: 1.1813x; 1.0442x over previous
//
#include <hip/hip_runtime.h>
#include <hip/hip_bf16.h>
#include <stdint.h>

#define SEQ 4096
#define DIN 1024
#define DOUT 1024

typedef __bf16 bf16;
typedef __bf16 bf16x4v __attribute__((ext_vector_type(4)));
typedef __bf16 bf16x8v __attribute__((ext_vector_type(8)));
typedef float f32x4 __attribute__((ext_vector_type(4)));

#define AS1 __attribute__((address_space(1)))
#define AS3 __attribute__((address_space(3)))

__device__ __forceinline__ void load_lds16(const void* g, void* l) {
  __builtin_amdgcn_global_load_lds((const AS1 uint32_t*)g, (AS3 uint32_t*)l, 16, 0, 0);
}
__device__ __forceinline__ int imin(int a, int b) { return a < b ? a : b; }

// m204 bijective XCD swizzle (works for any nwg)
__device__ __forceinline__ int xcd_swz(int orig, int nwg) {
  const int q = nwg >> 3, r = nwg & 7;
  const int x = orig & 7, idx = orig >> 3;
  return (x < r ? x * (q + 1) : r * (q + 1) + (x - r) * q) + idx;
}

// ---------------- fused cast fp32 -> bf16 for x, Wq, Wk, Wv (exact 1D grid) ---
__global__ __launch_bounds__(256) void cast_all_kernel(
    const float* __restrict__ x, const float* __restrict__ wq,
    const float* __restrict__ wk, const float* __restrict__ wv,
    bf16* __restrict__ xb, bf16* __restrict__ wqb,
    bf16* __restrict__ wkb, bf16* __restrict__ wvb) {
  const int id = blockIdx.x;
  const float* in; bf16* out; int blk;
  if (id < 4096) {
    in = x; out = xb; blk = id;
  } else {
    const int w = (id - 4096) >> 10;
    blk = (id - 4096) & 1023;
    in = (w == 0) ? wq : (w == 1) ? wk : wv;
    out = (w == 0) ? wqb : (w == 1) ? wkb : wvb;
  }
  const int i = (blk * 256 + threadIdx.x) * 4;
  float4 v = *reinterpret_cast<const float4*>(in + i);
  bf16x4v o;
  o[0] = (bf16)v.x; o[1] = (bf16)v.y; o[2] = (bf16)v.z; o[3] = (bf16)v.w;
  *reinterpret_cast<bf16x4v*>(out + i) = o;
}

// =============== 256x256 BT-GEMM core, BK=64, 8 waves, 128KB LDS ==============
// C[256x256] += A[brow..][k] * B[bcol..][k]^T, k in K-tiles [kt0, kt0+ktn) of 64.
// A: [M x lda], B: [N x ldb] bf16 row-major (K contiguous both).
// 512 threads = 8 waves (2M x 4N); wave output 128x64 = acc[2][2][4][2] f32x4.
// LDS (bytes): dbuf*65536 + {A0:0, A1:16384, B0:32768, B1:49152}; each half-tile
// 128 rows x 128B, XOR-swizzled: slot(r,c) holds global (r, c ^ ((r&7)<<4)).
// Stage side keeps LDS dest LINEAR (global_load_lds requirement) and swizzles
// the global SOURCE column; read side applies the same XOR (involution).
struct G256 {
  const char *pa, *pb;
  size_t lda2, ldb2;
  char* lds;
  int tid;
};

__device__ __forceinline__ void stage_tile(const G256& g, int sd, int kt) {
  const size_t kb = (size_t)kt * 128;
  char* d = g.lds + sd * 65536;
  const int to = g.tid * 16;
  load_lds16(g.pa + kb,                  d + 0     + to);  // A0 rows 0-63
  load_lds16(g.pa + kb + 64  * g.lda2,   d + 8192  + to);  // A0 rows 64-127
  load_lds16(g.pb + kb,                  d + 32768 + to);  // B0 rows 0-63
  load_lds16(g.pb + kb + 64  * g.ldb2,   d + 40960 + to);  // B0 rows 64-127
  load_lds16(g.pb + kb + 128 * g.ldb2,   d + 49152 + to);  // B1 rows 0-63
  load_lds16(g.pb + kb + 192 * g.ldb2,   d + 57344 + to);  // B1 rows 64-127
  load_lds16(g.pa + kb + 128 * g.lda2,   d + 16384 + to);  // A1 rows 0-63
  load_lds16(g.pa + kb + 192 * g.lda2,   d + 24576 + to);  // A1 rows 64-127
}

__device__ __forceinline__ void gemm256_core(const bf16* __restrict__ A,
                                             const bf16* __restrict__ B,
                                             int lda, int ldb, int brow, int bcol,
                                             int kt0, int ktn,
                                             f32x4 acc[2][2][4][2], char* lds) {
  const int tid = threadIdx.x;
  const int sr = tid >> 3;                              // staging row 0..63
  const int cs = ((tid & 7) << 4) ^ ((sr & 7) << 4);    // swizzled src byte col
  G256 g;
  g.lda2 = (size_t)lda * 2; g.ldb2 = (size_t)ldb * 2;
  g.pa = (const char*)A + (size_t)(brow + sr) * g.lda2 + cs;
  g.pb = (const char*)B + (size_t)(bcol + sr) * g.ldb2 + cs;
  g.lds = lds; g.tid = tid;

  const int lane = tid & 63, lrow = lane & 15, lkg = lane >> 4;
  const int wave = tid >> 6, wm = wave >> 2, wn = wave & 3;
  const int aReg = wm * 16384;                 // this wave's A half-tile
  const int bReg = 32768 + (wn >> 1) * 16384;  // this wave's B half-tile
  const int brow0 = (wn & 1) * 64;             // row base within B half
  const int swz = (lrow & 7) << 4;

  // prologue: stage K-tile 0, drain, barrier
  stage_tile(g, 0, kt0);
  asm volatile("s_waitcnt vmcnt(0)" ::: "memory");
  __builtin_amdgcn_s_barrier();
  __builtin_amdgcn_sched_barrier(0);

  for (int t = 0; t < ktn; ++t) {
    const int d = t & 1;
    // stage next K-tile (clamped dup on last iter; lands in unread dbuf)
    stage_tile(g, d ^ 1, kt0 + imin(t + 1, ktn - 1));
    const char* db = lds + d * 65536;

    bf16x8v a[4][2], b0[2][2], b1[2][2];
#pragma unroll
    for (int nt = 0; nt < 2; ++nt)
#pragma unroll
      for (int ks = 0; ks < 2; ++ks) {
        const int ck = (ks * 64 + lkg * 16) ^ swz;
        b0[nt][ks] = *(const bf16x8v*)(db + bReg + (brow0 + nt * 16 + lrow) * 128 + ck);
        b1[nt][ks] = *(const bf16x8v*)(db + bReg + (brow0 + 32 + nt * 16 + lrow) * 128 + ck);
      }
    // ---- mh = 0 (wave rows 0-63) ----
#pragma unroll
    for (int mt = 0; mt < 4; ++mt)
#pragma unroll
      for (int ks = 0; ks < 2; ++ks)
        a[mt][ks] = *(const bf16x8v*)(db + aReg + (mt * 16 + lrow) * 128 + ((ks * 64 + lkg * 16) ^ swz));
    __builtin_amdgcn_s_setprio(1);
#pragma unroll
    for (int mt = 0; mt < 4; ++mt)
#pragma unroll
      for (int nt = 0; nt < 2; ++nt)
#pragma unroll
        for (int ks = 0; ks < 2; ++ks) {
          acc[0][0][mt][nt] = __builtin_amdgcn_mfma_f32_16x16x32_bf16(a[mt][ks], b0[nt][ks], acc[0][0][mt][nt], 0, 0, 0);
          acc[0][1][mt][nt] = __builtin_amdgcn_mfma_f32_16x16x32_bf16(a[mt][ks], b1[nt][ks], acc[0][1][mt][nt], 0, 0, 0);
        }
    __builtin_amdgcn_s_setprio(0);
    // ---- mh = 1 (wave rows 64-127) ----
#pragma unroll
    for (int mt = 0; mt < 4; ++mt)
#pragma unroll
      for (int ks = 0; ks < 2; ++ks)
        a[mt][ks] = *(const bf16x8v*)(db + aReg + ((64 + mt * 16 + lrow) * 128) + ((ks * 64 + lkg * 16) ^ swz));
    __builtin_amdgcn_s_setprio(1);
#pragma unroll
    for (int mt = 0; mt < 4; ++mt)
#pragma unroll
      for (int nt = 0; nt < 2; ++nt)
#pragma unroll
        for (int ks = 0; ks < 2; ++ks) {
          acc[1][1][mt][nt] = __builtin_amdgcn_mfma_f32_16x16x32_bf16(a[mt][ks], b1[nt][ks], acc[1][1][mt][nt], 0, 0, 0);
          acc[1][0][mt][nt] = __builtin_amdgcn_mfma_f32_16x16x32_bf16(a[mt][ks], b0[nt][ks], acc[1][0][mt][nt], 0, 0, 0);
        }
    __builtin_amdgcn_s_setprio(0);
    // boundary: next tile fully landed + all waves done reading this dbuf
    asm volatile("s_waitcnt vmcnt(0)" ::: "memory");
    __builtin_amdgcn_s_barrier();
    __builtin_amdgcn_sched_barrier(0);
  }
}

#define ACC256_INIT()                         \
  f32x4 acc[2][2][4][2];                      \
  {                                           \
    f32x4 z = {0.f, 0.f, 0.f, 0.f};           \
    for (int a1 = 0; a1 < 2; ++a1)            \
      for (int a2 = 0; a2 < 2; ++a2)          \
        for (int a3 = 0; a3 < 4; ++a3)        \
          for (int a4 = 0; a4 < 2; ++a4) acc[a1][a2][a3][a4] = z; \
  }

// epilogue index bases (per thread)
#define EPI_BASES()                                             \
  const int lane = threadIdx.x & 63;                            \
  const int wave = threadIdx.x >> 6;                            \
  const int wm = wave >> 2, wn = wave & 3;                      \
  const int rb = wm * 128 + ((lane >> 4) << 2);                 \
  const int cb = wn * 64 + (lane & 15);

// ---------------- QKV projection ----------------------------------------------
// grid 192 = 3z x 16bi x 4bj (bj inner), XCD-swizzled. K-tiles: 16.
__global__ __launch_bounds__(512, 2) void qkv_kernel(const bf16* __restrict__ xb,
                                                     const bf16* __restrict__ Wq,
                                                     const bf16* __restrict__ Wk,
                                                     const bf16* __restrict__ Wv,
                                                     bf16* __restrict__ Q,
                                                     bf16* __restrict__ K,
                                                     bf16* __restrict__ Vt) {
  extern __shared__ char lds[];
  const int l = xcd_swz(blockIdx.x, 192);
  const int z = l >> 6, tt = l & 63, bi = tt >> 2, bj = tt & 3;
  const bf16* W = (z == 0) ? Wq : (z == 1) ? Wk : Wv;
  ACC256_INIT();
  gemm256_core(xb, W, DIN, DIN, bi * 256, bj * 256, 0, 16, acc, lds);
  EPI_BASES();
  const int rbase = bi * 256 + rb, cbase = bj * 256 + cb;
  if (z < 2) {
    bf16* O = (z == 0) ? Q : K;
#pragma unroll
    for (int mh = 0; mh < 2; ++mh)
#pragma unroll
      for (int nh = 0; nh < 2; ++nh)
#pragma unroll
        for (int mt = 0; mt < 4; ++mt)
#pragma unroll
          for (int nt = 0; nt < 2; ++nt)
#pragma unroll
            for (int j = 0; j < 4; ++j)
              O[(size_t)(rbase + mh * 64 + mt * 16 + j) * DOUT + (cbase + nh * 32 + nt * 16)] =
                  (bf16)acc[mh][nh][mt][nt][j];
  } else {
#pragma unroll
    for (int mh = 0; mh < 2; ++mh)
#pragma unroll
      for (int nh = 0; nh < 2; ++nh)
#pragma unroll
        for (int mt = 0; mt < 4; ++mt)
#pragma unroll
          for (int nt = 0; nt < 2; ++nt)
#pragma unroll
            for (int j = 0; j < 4; ++j)
              Vt[(size_t)(cbase + nh * 32 + nt * 16) * SEQ + (rbase + mh * 64 + mt * 16 + j)] =
                  (bf16)acc[mh][nh][mt][nt][j];
  }
}

// ---------------- scores = Q K^T * scale, triangular 256-grid ------------------
// grid 136 triangular over 16x16 (bi-major, bj inner), XCD-swizzled.
__global__ __launch_bounds__(512, 2) void scores_kernel(const bf16* __restrict__ Q,
                                                        const bf16* __restrict__ Km,
                                                        float* __restrict__ Sc) {
  extern __shared__ char lds[];
  const int t = xcd_swz(blockIdx.x, 136);
  int bi = (int)((sqrtf(8.0f * (float)t + 1.0f) - 1.0f) * 0.5f);
  while ((bi + 1) * (bi + 2) / 2 <= t) ++bi;
  while (bi * (bi + 1) / 2 > t) --bi;
  const int bj = t - bi * (bi + 1) / 2;
  ACC256_INIT();
  gemm256_core(Q, Km, DOUT, DOUT, bi * 256, bj * 256, 0, 16, acc, lds);
  EPI_BASES();
  const int rbase = bi * 256 + rb, cbase = bj * 256 + cb;
  const float scale = 0.03125f;  // 1/sqrt(1024)
#pragma unroll
  for (int mh = 0; mh < 2; ++mh)
#pragma unroll
    for (int nh = 0; nh < 2; ++nh)
#pragma unroll
      for (int mt = 0; mt < 4; ++mt)
#pragma unroll
        for (int nt = 0; nt < 2; ++nt)
#pragma unroll
          for (int j = 0; j < 4; ++j)
            Sc[(size_t)(rbase + mh * 64 + mt * 16 + j) * SEQ + (cbase + nh * 32 + nt * 16)] =
                acc[mh][nh][mt][nt][j] * scale;
}

// ---------------- row softmax (vectorized): zero-pad to 256-col boundary ------
__global__ __launch_bounds__(256) void softmax_kernel(const float* __restrict__ Sc,
                                                      bf16* __restrict__ P) {
  __shared__ float rowbuf[SEQ];
  __shared__ float red[8];
  const int r = blockIdx.x;
  const int n = r + 1;
  const int nw4 = ((r >> 8) + 1) << 6;  // padded row length / 4 (256-col blocks)
  const int tid = threadIdx.x;
  const float* src = Sc + (size_t)r * SEQ;
  const float NEG = -__builtin_inff();

  float lmax = NEG;
  for (int g = tid; g < nw4; g += 256) {
    float4 v = reinterpret_cast<const float4*>(src)[g];
    const int b = g * 4;
    v.x = (b + 0 < n) ? v.x : NEG;
    v.y = (b + 1 < n) ? v.y : NEG;
    v.z = (b + 2 < n) ? v.z : NEG;
    v.w = (b + 3 < n) ? v.w : NEG;
    reinterpret_cast<float4*>(rowbuf)[g] = v;
    lmax = fmaxf(fmaxf(lmax, fmaxf(v.x, v.y)), fmaxf(v.z, v.w));
  }
#pragma unroll
  for (int m = 32; m >= 1; m >>= 1) lmax = fmaxf(lmax, __shfl_xor(lmax, m, 64));
  if ((tid & 63) == 0) red[tid >> 6] = lmax;
  __syncthreads();
  const float rmax = fmaxf(fmaxf(red[0], red[1]), fmaxf(red[2], red[3]));

  float lsum = 0.f;
  for (int g = tid; g < nw4; g += 256) {
    float4 v = reinterpret_cast<const float4*>(rowbuf)[g];
    v.x = __expf(v.x - rmax);
    v.y = __expf(v.y - rmax);
    v.z = __expf(v.z - rmax);
    v.w = __expf(v.w - rmax);
    reinterpret_cast<float4*>(rowbuf)[g] = v;
    lsum += v.x + v.y + v.z + v.w;
  }
#pragma unroll
  for (int m = 32; m >= 1; m >>= 1) lsum += __shfl_xor(lsum, m, 64);
  if ((tid & 63) == 0) red[4 + (tid >> 6)] = lsum;
  __syncthreads();
  const float inv = 1.0f / (red[4] + red[5] + red[6] + red[7]);

  bf16* dst = P + (size_t)r * SEQ;
  for (int g = tid; g < nw4; g += 256) {
    float4 v = reinterpret_cast<const float4*>(rowbuf)[g];
    bf16x4v o;
    o[0] = (bf16)(v.x * inv);
    o[1] = (bf16)(v.y * inv);
    o[2] = (bf16)(v.z * inv);
    o[3] = (bf16)(v.w * inv);
    *reinterpret_cast<bf16x4v*>(dst + g * 4) = o;
  }
}

// ---------------- out += P @ V (balanced split-K, atomic accumulate) ----------
// grid 204 = 51 chunk-slots x 4 bj (bj inner), XCD-swizzled.
// Per bi: Ti=(bi+1)*4 K-tiles, nch=ceil((bi+1)/3) chunks, balanced (<=12 tiles).
__global__ __launch_bounds__(512, 2) void pv_kernel(const bf16* __restrict__ P,
                                                    const bf16* __restrict__ Vt,
                                                    float* __restrict__ Out) {
  extern __shared__ char lds[];
  const int l = xcd_swz(blockIdx.x, 204);
  const int bj = l & 3;
  int c = l >> 2, bi = 0;
  for (;;) {
    const int nch = (bi + 3) / 3;  // ceil((bi+1)/3)
    if (c < nch) break;
    c -= nch; ++bi;
  }
  const int nch = (bi + 3) / 3;
  const int Ti = (bi + 1) * 4;
  const int base = Ti / nch, rem = Ti % nch;
  const int kt0 = c * base + imin(c, rem);
  const int ktn = base + (c < rem ? 1 : 0);
  ACC256_INIT();
  gemm256_core(P, Vt, SEQ, SEQ, bi * 256, bj * 256, kt0, ktn, acc, lds);
  EPI_BASES();
  const int rbase = bi * 256 + rb, cbase = bj * 256 + cb;
  if (nch == 1) {
#pragma unroll
    for (int mh = 0; mh < 2; ++mh)
#pragma unroll
      for (int nh = 0; nh < 2; ++nh)
#pragma unroll
        for (int mt = 0; mt < 4; ++mt)
#pragma unroll
          for (int nt = 0; nt < 2; ++nt)
#pragma unroll
            for (int j = 0; j < 4; ++j)
              Out[(size_t)(rbase + mh * 64 + mt * 16 + j) * DOUT + (cbase + nh * 32 + nt * 16)] =
                  acc[mh][nh][mt][nt][j];
  } else {
#pragma unroll
    for (int mh = 0; mh < 2; ++mh)
#pragma unroll
      for (int nh = 0; nh < 2; ++nh)
#pragma unroll
        for (int mt = 0; mt < 4; ++mt)
#pragma unroll
          for (int nt = 0; nt < 2; ++nt)
#pragma unroll
            for (int j = 0; j < 4; ++j)
              atomicAdd(&Out[(size_t)(rbase + mh * 64 + mt * 16 + j) * DOUT + (cbase + nh * 32 + nt * 16)],
                        acc[mh][nh][mt][nt][j]);
  }
}

extern "C" void kernel_launch(void* const* d_in, const int* in_sizes, int n_in,
                              void* d_out, int out_size, void* d_ws, size_t ws_size,
                              hipStream_t stream) {
  const float* x  = (const float*)d_in[0];
  const float* Wq = (const float*)d_in[1];
  const float* Wk = (const float*)d_in[2];
  const float* Wv = (const float*)d_in[3];
  float* Out = (float*)d_out;

  char* base = (char*)d_ws;
  bf16* xb  = (bf16*)(base + 0);          //  8 MB  [4096x1024]
  bf16* wqb = (bf16*)(base + 8388608);    //  2 MB
  bf16* wkb = (bf16*)(base + 10485760);   //  2 MB
  bf16* wvb = (bf16*)(base + 12582912);   //  2 MB
  bf16* Qb  = (bf16*)(base + 14680064);   //  8 MB
  bf16* Kb  = (bf16*)(base + 23068672);   //  8 MB
  bf16* Vtb = (bf16*)(base + 31457280);   //  8 MB  [1024x4096] transposed
  float* Sc = (float*)(base + 39845888);  // 64 MB  [4096x4096] fp32
  bf16* P   = (bf16*)(base + 106954752);  // 32 MB  [4096x4096] bf16

  // allow 128KB dynamic LDS (idempotent; host-side, graph-capture safe)
  (void)hipFuncSetAttribute((const void*)qkv_kernel,
                            hipFuncAttributeMaxDynamicSharedMemorySize, 131072);
  (void)hipFuncSetAttribute((const void*)scores_kernel,
                            hipFuncAttributeMaxDynamicSharedMemorySize, 131072);
  (void)hipFuncSetAttribute((const void*)pv_kernel,
                            hipFuncAttributeMaxDynamicSharedMemorySize, 131072);

  hipMemsetAsync(d_out, 0, (size_t)out_size * sizeof(float), stream);

  cast_all_kernel<<<7168, 256, 0, stream>>>(x, Wq, Wk, Wv, xb, wqb, wkb, wvb);

  qkv_kernel<<<192, 512, 131072, stream>>>(xb, wqb, wkb, wvb, Qb, Kb, Vtb);
  scores_kernel<<<136, 512, 131072, stream>>>(Qb, Kb, Sc);
  softmax_kernel<<<SEQ, 256, 0, stream>>>(Sc, P);
  pv_kernel<<<204, 512, 131072, stream>>>(P, Vtb, Out);
}